// Round 3
// baseline (275.027 us; speedup 1.0000x reference)
//
#include <hip/hip_runtime.h>
#include <hip/hip_bf16.h>

// ---------- types ----------
typedef __attribute__((ext_vector_type(4))) float  f32x4;
typedef __attribute__((ext_vector_type(8))) short  bf16x8;   // 8 bf16 in 4 VGPRs
typedef __attribute__((ext_vector_type(8))) unsigned short u16x8;
typedef __attribute__((ext_vector_type(4))) unsigned short u16x4;

__device__ __forceinline__ unsigned short f2bf(float f) {
    union { float f; unsigned u; } v; v.f = f;
    unsigned u = v.u;
    unsigned r = u + 0x7fffu + ((u >> 16) & 1u);   // round-to-nearest-even
    return (unsigned short)(r >> 16);
}

__device__ __forceinline__ void gload16(const void* g, void* l) {
    __builtin_amdgcn_global_load_lds((const __attribute__((address_space(1))) unsigned*)g,
                                     (__attribute__((address_space(3))) unsigned*)l, 16, 0, 0);
}

// ---------- problem constants ----------
// B=2, T=64, CH=512, Hs=24, Ws=24, HW=576, P=1152, DIM=256, HEADS=8, HD=32
// xb layout: p-major, xb[(p*64 + t)*256 + c]

// ---------- K0: weights fp32 -> bf16 ----------
__global__ void cvt_weights(const float* __restrict__ qkv_w, const float* __restrict__ proj_w,
                            unsigned short* __restrict__ wq, unsigned short* __restrict__ wp) {
    int i = blockIdx.x * 256 + threadIdx.x;          // 262144 total
    if (i < 196608) wq[i] = f2bf(qkv_w[i]);
    else            wp[i - 196608] = f2bf(proj_w[i - 196608]);
}

// ---------- K1: copy a-half ----------
__global__ void copy_a(const float* __restrict__ x, float* __restrict__ out) {
    long long i = (long long)blockIdx.x * 256 + threadIdx.x;   // float4 index
    int chunk = (int)(i / 36864);            // (b*64+t), 128 slabs
    int r     = (int)(i % 36864);
    size_t off = (size_t)chunk * 73728 + r;
    ((float4*)out)[off] = ((const float4*)x)[off];
}

// ---------- K2: transpose b-half -> xb[(p*64+t)*256 + c] bf16 ----------
__global__ __launch_bounds__(256) void transpose_b(const float* __restrict__ x,
                                                   unsigned short* __restrict__ xb) {
    __shared__ unsigned short tile[256][72];
    const int bt  = blockIdx.x;                       // b*64+t
    const int hw0 = blockIdx.y * 64;
    const int tid = threadIdx.x;
    const float* src = x + ((size_t)bt * 512 + 256) * 576 + hw0;
    const int c_sub = tid >> 4, l16 = tid & 15;
    #pragma unroll
    for (int it = 0; it < 16; ++it) {
        int cc = it * 16 + c_sub;
        const float4 v = *(const float4*)(src + (size_t)cc * 576 + l16 * 4);
        tile[cc][l16 * 4 + 0] = f2bf(v.x);
        tile[cc][l16 * 4 + 1] = f2bf(v.y);
        tile[cc][l16 * 4 + 2] = f2bf(v.z);
        tile[cc][l16 * 4 + 3] = f2bf(v.w);
    }
    __syncthreads();
    const int row = tid >> 2;                 // hw within tile
    const int cs  = (tid & 3) * 64;
    const int b = bt >> 6, t = bt & 63;
    size_t m = ((size_t)(b * 576 + hw0 + row)) * 64 + t;   // p-major
    unsigned short* dst = xb + m * 256 + cs;
    #pragma unroll
    for (int q = 0; q < 8; ++q) {
        u16x8 v;
        #pragma unroll
        for (int u = 0; u < 8; ++u) v[u] = tile[cs + q * 8 + u][row];
        *(u16x8*)(dst + q * 8) = v;
    }
}

// ---------- K3: fused qkv + attention + proj, one block per pixel ----------
// 512 threads = 8 waves; wave w owns head w.
__global__ __launch_bounds__(512, 2) void fused_block(
    const unsigned short* __restrict__ xb,
    const unsigned short* __restrict__ wqkv,   // [768][256] bf16
    const unsigned short* __restrict__ wproj,  // [256][256] bf16
    const float* __restrict__ qkv_b,
    const float* __restrict__ proj_b,
    const float* __restrict__ rpb,
    float* __restrict__ out)
{
    __shared__ unsigned short xs[16384];      // 64 t-rows x 256 c (XOR-swizzled 16B units); reused as att
    __shared__ unsigned short wbuf[8][7424];  // per wave: Q[0,2560) K[2560,5120) Vt[5120,7424); P overlays [0,4608)
    __shared__ float bias_s[1016];            // rpb as-is: [127][8]

    const int tid  = threadIdx.x;
    const int lane = tid & 63, w = tid >> 6;
    const int c = lane & 15, g = lane >> 4;
    const int c7 = c & 7;
    const int bid = blockIdx.x;
    const int p  = (bid & 7) * 144 + (bid >> 3);   // XCD-contiguous pixels
    const int b  = p / 576, hw = p % 576;

    // ---- stage xs: 32 KB contiguous, source pre-swizzled so linear LDS holds swizzled rows
    const unsigned short* src = xb + (size_t)p * 16384;
    #pragma unroll
    for (int it = 0; it < 4; ++it) {
        int U = it * 512 + tid;
        int r = U >> 5, u = U & 31;
        gload16(src + r * 256 + ((u ^ (r & 7)) << 3), &xs[U << 3]);
    }
    if (tid < 1016) bias_s[tid] = rpb[tid];
    __syncthreads();

    unsigned short* Q  = &wbuf[w][0];      // [64][40]
    unsigned short* Kl = &wbuf[w][2560];   // [64][40]
    unsigned short* Vt = &wbuf[w][5120];   // [32][72]
    unsigned short* P  = &wbuf[w][0];      // [64][72], overlays Q+K after QK^T

    // ---- QKV GEMM for head w: D[n][t], A = W rows, B = xs rows ----
    {
        f32x4 acc[3][2][4] = {};
        #pragma unroll
        for (int ks = 0; ks < 8; ++ks) {
            bf16x8 bx[4];
            #pragma unroll
            for (int b2 = 0; b2 < 4; ++b2)
                bx[b2] = *(const bf16x8*)(&xs[(b2 * 16 + c) * 256 + (((ks * 4 + g) ^ c7) << 3)]);
            #pragma unroll
            for (int mat = 0; mat < 3; ++mat) {
                bf16x8 af[2];
                #pragma unroll
                for (int a2 = 0; a2 < 2; ++a2)
                    af[a2] = *(const bf16x8*)(wqkv + (size_t)(mat * 256 + w * 32 + a2 * 16 + c) * 256 + ks * 32 + g * 8);
                #pragma unroll
                for (int a2 = 0; a2 < 2; ++a2)
                    #pragma unroll
                    for (int b2 = 0; b2 < 4; ++b2)
                        acc[mat][a2][b2] = __builtin_amdgcn_mfma_f32_16x16x32_bf16(af[a2], bx[b2], acc[mat][a2][b2], 0, 0, 0);
            }
        }
        const float scale = 0.17677669529663687f;   // 1/sqrt(32)
        #pragma unroll
        for (int a2 = 0; a2 < 2; ++a2) {
            float4 bq = *(const float4*)(qkv_b +       w * 32 + a2 * 16 + g * 4);
            float4 bk = *(const float4*)(qkv_b + 256 + w * 32 + a2 * 16 + g * 4);
            float4 bv = *(const float4*)(qkv_b + 512 + w * 32 + a2 * 16 + g * 4);
            #pragma unroll
            for (int b2 = 0; b2 < 4; ++b2) {
                int t = b2 * 16 + c;
                u16x4 vq, vk;
                vq[0] = f2bf((acc[0][a2][b2][0] + bq.x) * scale);
                vq[1] = f2bf((acc[0][a2][b2][1] + bq.y) * scale);
                vq[2] = f2bf((acc[0][a2][b2][2] + bq.z) * scale);
                vq[3] = f2bf((acc[0][a2][b2][3] + bq.w) * scale);
                *(u16x4*)(&Q[t * 40 + a2 * 16 + g * 4]) = vq;
                vk[0] = f2bf(acc[1][a2][b2][0] + bk.x);
                vk[1] = f2bf(acc[1][a2][b2][1] + bk.y);
                vk[2] = f2bf(acc[1][a2][b2][2] + bk.z);
                vk[3] = f2bf(acc[1][a2][b2][3] + bk.w);
                *(u16x4*)(&Kl[t * 40 + a2 * 16 + g * 4]) = vk;
                Vt[(a2 * 16 + g * 4 + 0) * 72 + t] = f2bf(acc[2][a2][b2][0] + bv.x);
                Vt[(a2 * 16 + g * 4 + 1) * 72 + t] = f2bf(acc[2][a2][b2][1] + bv.y);
                Vt[(a2 * 16 + g * 4 + 2) * 72 + t] = f2bf(acc[2][a2][b2][2] + bv.z);
                Vt[(a2 * 16 + g * 4 + 3) * 72 + t] = f2bf(acc[2][a2][b2][3] + bv.w);
            }
        }
    }

    // ---- QK^T (K-dim = 32 = one MFMA step) ----
    bf16x8 qf[4], kf[4];
    #pragma unroll
    for (int mt = 0; mt < 4; ++mt) qf[mt] = *(const bf16x8*)(&Q[(mt * 16 + c) * 40 + g * 8]);
    #pragma unroll
    for (int nt = 0; nt < 4; ++nt) kf[nt] = *(const bf16x8*)(&Kl[(nt * 16 + c) * 40 + g * 8]);
    f32x4 S[4][4] = {};
    #pragma unroll
    for (int mt = 0; mt < 4; ++mt)
        #pragma unroll
        for (int nt = 0; nt < 4; ++nt)
            S[mt][nt] = __builtin_amdgcn_mfma_f32_16x16x32_bf16(qf[mt], kf[nt], S[mt][nt], 0, 0, 0);

    // ---- softmax (full row available), P -> LDS (overlays Q/K) ----
    #pragma unroll
    for (int mt = 0; mt < 4; ++mt) {
        #pragma unroll
        for (int r = 0; r < 4; ++r) {
            int i = mt * 16 + g * 4 + r;
            float vals[4];
            #pragma unroll
            for (int nt = 0; nt < 4; ++nt) {
                int j = nt * 16 + c;
                float v = S[mt][nt][r] + bias_s[(j - i + 63) * 8 + w];
                vals[nt] = (j > i) ? -1e30f : v;
            }
            float mx = fmaxf(fmaxf(vals[0], vals[1]), fmaxf(vals[2], vals[3]));
            #pragma unroll
            for (int off = 1; off < 16; off <<= 1) mx = fmaxf(mx, __shfl_xor(mx, off, 64));
            float sum = 0.f;
            #pragma unroll
            for (int nt = 0; nt < 4; ++nt) { vals[nt] = __expf(vals[nt] - mx); sum += vals[nt]; }
            #pragma unroll
            for (int off = 1; off < 16; off <<= 1) sum += __shfl_xor(sum, off, 64);
            float inv = 1.0f / sum;
            #pragma unroll
            for (int nt = 0; nt < 4; ++nt) P[i * 72 + nt * 16 + c] = f2bf(vals[nt] * inv);
        }
    }

    // ---- PV: O[i][d] ----
    f32x4 O[4][2] = {};
    #pragma unroll
    for (int kk = 0; kk < 2; ++kk) {
        bf16x8 pa[4], vb[2];
        #pragma unroll
        for (int mt = 0; mt < 4; ++mt)
            pa[mt] = *(const bf16x8*)(&P[(mt * 16 + c) * 72 + kk * 32 + g * 8]);
        #pragma unroll
        for (int nt = 0; nt < 2; ++nt)
            vb[nt] = *(const bf16x8*)(&Vt[(nt * 16 + c) * 72 + kk * 32 + g * 8]);
        #pragma unroll
        for (int mt = 0; mt < 4; ++mt)
            #pragma unroll
            for (int nt = 0; nt < 2; ++nt)
                O[mt][nt] = __builtin_amdgcn_mfma_f32_16x16x32_bf16(pa[mt], vb[nt], O[mt][nt], 0, 0, 0);
    }

    __syncthreads();   // all waves done reading xs
    // ---- O -> att (xs region, swizzled units) ----
    #pragma unroll
    for (int mt = 0; mt < 4; ++mt)
        #pragma unroll
        for (int nt = 0; nt < 2; ++nt)
            #pragma unroll
            for (int r = 0; r < 4; ++r) {
                int t  = mt * 16 + g * 4 + r;
                int cg = w * 32 + nt * 16 + c;
                xs[t * 256 + (((cg >> 3) ^ (t & 7)) << 3) + (cg & 7)] = f2bf(O[mt][nt][r]);
            }
    __syncthreads();

    // ---- proj: D[n][t], A = Wp rows (wave's 32 n), B = att rows ----
    f32x4 ap[2][4] = {};
    #pragma unroll
    for (int ks = 0; ks < 8; ++ks) {
        bf16x8 af[2], bx[4];
        #pragma unroll
        for (int a2 = 0; a2 < 2; ++a2)
            af[a2] = *(const bf16x8*)(wproj + (size_t)(w * 32 + a2 * 16 + c) * 256 + ks * 32 + g * 8);
        #pragma unroll
        for (int b2 = 0; b2 < 4; ++b2)
            bx[b2] = *(const bf16x8*)(&xs[(b2 * 16 + c) * 256 + (((ks * 4 + g) ^ c7) << 3)]);
        #pragma unroll
        for (int a2 = 0; a2 < 2; ++a2)
            #pragma unroll
            for (int b2 = 0; b2 < 4; ++b2)
                ap[a2][b2] = __builtin_amdgcn_mfma_f32_16x16x32_bf16(af[a2], bx[b2], ap[a2][b2], 0, 0, 0);
    }
    #pragma unroll
    for (int a2 = 0; a2 < 2; ++a2) {
        int n = w * 32 + a2 * 16 + g * 4;
        float4 pb = *(const float4*)(proj_b + n);
        #pragma unroll
        for (int b2 = 0; b2 < 4; ++b2) {
            int t = b2 * 16 + c;
            float* dst = out + ((size_t)((b * 64 + t) * 512 + 256 + n)) * 576 + hw;
            dst[0]        = ap[a2][b2][0] + pb.x;
            dst[576]      = ap[a2][b2][1] + pb.y;
            dst[2 * 576]  = ap[a2][b2][2] + pb.z;
            dst[3 * 576]  = ap[a2][b2][3] + pb.w;
        }
    }
}

// ---------- launcher ----------
extern "C" void kernel_launch(void* const* d_in, const int* in_sizes, int n_in,
                              void* d_out, int out_size, void* d_ws, size_t ws_size,
                              hipStream_t stream) {
    (void)in_sizes; (void)n_in; (void)out_size;
    const float* x      = (const float*)d_in[0];
    const float* rpb    = (const float*)d_in[1];
    const float* qkv_w  = (const float*)d_in[2];
    const float* qkv_b  = (const float*)d_in[3];
    const float* proj_w = (const float*)d_in[4];
    const float* proj_b = (const float*)d_in[5];
    float* out = (float*)d_out;

    // ws: wq 393216 | wp 131072 | xb 37748736
    char* ws = (char*)d_ws;
    unsigned short* wq = (unsigned short*)ws;
    unsigned short* wp = (unsigned short*)(ws + 393216);
    unsigned short* xb = (unsigned short*)(ws + 524288);
    if (ws_size < (size_t)524288 + 37748736) return;

    cvt_weights<<<1024, 256, 0, stream>>>(qkv_w, proj_w, wq, wp);
    copy_a<<<18432, 256, 0, stream>>>(x, out);
    transpose_b<<<dim3(128, 9), 256, 0, stream>>>(x, xb);
    fused_block<<<1152, 512, 0, stream>>>(xb, wq, wp, qkv_b, proj_b, rpb, out);
}

// Round 4
// 270.296 us; speedup vs baseline: 1.0175x; 1.0175x over previous
//
#include <hip/hip_runtime.h>
#include <hip/hip_bf16.h>

// ---------- types ----------
typedef __attribute__((ext_vector_type(4))) float  f32x4;
typedef __attribute__((ext_vector_type(8))) short  bf16x8;   // 8 bf16 in 4 VGPRs
typedef __attribute__((ext_vector_type(8))) unsigned short u16x8;
typedef __attribute__((ext_vector_type(4))) unsigned short u16x4;

__device__ __forceinline__ unsigned short f2bf(float f) {
    union { float f; unsigned u; } v; v.f = f;
    unsigned u = v.u;
    unsigned r = u + 0x7fffu + ((u >> 16) & 1u);   // round-to-nearest-even
    return (unsigned short)(r >> 16);
}

__device__ __forceinline__ void gload16(const void* g, void* l) {
    __builtin_amdgcn_global_load_lds((const __attribute__((address_space(1))) unsigned*)g,
                                     (__attribute__((address_space(3))) unsigned*)l, 16, 0, 0);
}

// ---------- problem constants ----------
// B=2, T=64, CH=512, Hs=24, Ws=24, HW=576, P=1152, DIM=256, HEADS=8, HD=32
// xb layout: p-major, xb[(p*64 + t)*256 + c]

// ---------- K0: weights fp32 -> bf16 ----------
__global__ void cvt_weights(const float* __restrict__ qkv_w, const float* __restrict__ proj_w,
                            unsigned short* __restrict__ wq, unsigned short* __restrict__ wp) {
    int i = blockIdx.x * 256 + threadIdx.x;          // 262144 total
    if (i < 196608) wq[i] = f2bf(qkv_w[i]);
    else            wp[i - 196608] = f2bf(proj_w[i - 196608]);
}

// ---------- K1: copy a-half ----------
__global__ void copy_a(const float* __restrict__ x, float* __restrict__ out) {
    long long i = (long long)blockIdx.x * 256 + threadIdx.x;   // float4 index
    int chunk = (int)(i / 36864);            // (b*64+t), 128 slabs
    int r     = (int)(i % 36864);
    size_t off = (size_t)chunk * 73728 + r;
    ((float4*)out)[off] = ((const float4*)x)[off];
}

// ---------- K2: transpose b-half -> xb[(p*64+t)*256 + c] bf16 ----------
__global__ __launch_bounds__(256) void transpose_b(const float* __restrict__ x,
                                                   unsigned short* __restrict__ xb) {
    __shared__ unsigned short tile[256][72];
    const int bt  = blockIdx.x;                       // b*64+t
    const int hw0 = blockIdx.y * 64;
    const int tid = threadIdx.x;
    const float* src = x + ((size_t)bt * 512 + 256) * 576 + hw0;
    const int c_sub = tid >> 4, l16 = tid & 15;
    #pragma unroll
    for (int it = 0; it < 16; ++it) {
        int cc = it * 16 + c_sub;
        const float4 v = *(const float4*)(src + (size_t)cc * 576 + l16 * 4);
        tile[cc][l16 * 4 + 0] = f2bf(v.x);
        tile[cc][l16 * 4 + 1] = f2bf(v.y);
        tile[cc][l16 * 4 + 2] = f2bf(v.z);
        tile[cc][l16 * 4 + 3] = f2bf(v.w);
    }
    __syncthreads();
    const int row = tid >> 2;                 // hw within tile
    const int cs  = (tid & 3) * 64;
    const int b = bt >> 6, t = bt & 63;
    size_t m = ((size_t)(b * 576 + hw0 + row)) * 64 + t;   // p-major
    unsigned short* dst = xb + m * 256 + cs;
    #pragma unroll
    for (int q = 0; q < 8; ++q) {
        u16x8 v;
        #pragma unroll
        for (int u = 0; u < 8; ++u) v[u] = tile[cs + q * 8 + u][row];
        *(u16x8*)(dst + q * 8) = v;
    }
}

// ---------- K3: fused qkv + attention + proj, one block per pixel ----------
// 512 threads = 8 waves; wave w owns head w.
// LDS caps occupancy at 1 block/CU (= 2 waves/EU), so let the compiler use up
// to 256 VGPRs instead of spilling at the 128 (4-wave) heuristic cap.
__global__ __launch_bounds__(512) __attribute__((amdgpu_waves_per_eu(2, 2)))
void fused_block(
    const unsigned short* __restrict__ xb,
    const unsigned short* __restrict__ wqkv,   // [768][256] bf16
    const unsigned short* __restrict__ wproj,  // [256][256] bf16
    const float* __restrict__ qkv_b,
    const float* __restrict__ proj_b,
    const float* __restrict__ rpb,
    float* __restrict__ out)
{
    __shared__ unsigned short xs[16384];      // 64 t-rows x 256 c (XOR-swizzled 16B units); reused as att
    __shared__ unsigned short wbuf[8][7424];  // per wave: Q[0,2560) K[2560,5120) Vt[5120,7424); P overlays [0,4608)
    __shared__ float bias_s[8][64];           // bias_s[h][d], d = j-i+63 (only d<=63 is ever unmasked)

    const int tid  = threadIdx.x;
    const int lane = tid & 63, w = tid >> 6;
    const int c = lane & 15, g = lane >> 4;
    const int c7 = c & 7;
    const int bid = blockIdx.x;
    const int p  = (bid & 7) * 144 + (bid >> 3);   // XCD-contiguous pixels
    const int b  = p / 576, hw = p % 576;

    // ---- stage xs: 32 KB contiguous, source pre-swizzled so linear LDS holds swizzled rows
    const unsigned short* src = xb + (size_t)p * 16384;
    #pragma unroll
    for (int it = 0; it < 4; ++it) {
        int U = it * 512 + tid;
        int r = U >> 5, u = U & 31;
        gload16(src + r * 256 + ((u ^ (r & 7)) << 3), &xs[U << 3]);
    }
    // bias: rpb[d][h] -> bias_s[h][d], d<64 (d>=64 is causal-masked, never used)
    bias_s[tid & 7][tid >> 3] = rpb[tid];
    __syncthreads();

    unsigned short* Q  = &wbuf[w][0];      // [64][40]
    unsigned short* Kl = &wbuf[w][2560];   // [64][40]
    unsigned short* Vt = &wbuf[w][5120];   // [32][72]
    unsigned short* P  = &wbuf[w][0];      // [64][72], overlays Q+K after QK^T
    const float* bias_w = bias_s[w];

    // ---- QKV GEMM for head w: D[n][t], A = W rows, B = xs rows ----
    {
        f32x4 acc[3][2][4] = {};
        #pragma unroll
        for (int ks = 0; ks < 8; ++ks) {
            bf16x8 bx[4];
            #pragma unroll
            for (int b2 = 0; b2 < 4; ++b2)
                bx[b2] = *(const bf16x8*)(&xs[(b2 * 16 + c) * 256 + (((ks * 4 + g) ^ c7) << 3)]);
            #pragma unroll
            for (int mat = 0; mat < 3; ++mat) {
                bf16x8 af[2];
                #pragma unroll
                for (int a2 = 0; a2 < 2; ++a2)
                    af[a2] = *(const bf16x8*)(wqkv + (size_t)(mat * 256 + w * 32 + a2 * 16 + c) * 256 + ks * 32 + g * 8);
                #pragma unroll
                for (int a2 = 0; a2 < 2; ++a2)
                    #pragma unroll
                    for (int b2 = 0; b2 < 4; ++b2)
                        acc[mat][a2][b2] = __builtin_amdgcn_mfma_f32_16x16x32_bf16(af[a2], bx[b2], acc[mat][a2][b2], 0, 0, 0);
            }
        }
        const float scale = 0.17677669529663687f;   // 1/sqrt(32)
        #pragma unroll
        for (int a2 = 0; a2 < 2; ++a2) {
            float4 bq = *(const float4*)(qkv_b +       w * 32 + a2 * 16 + g * 4);
            float4 bk = *(const float4*)(qkv_b + 256 + w * 32 + a2 * 16 + g * 4);
            float4 bv = *(const float4*)(qkv_b + 512 + w * 32 + a2 * 16 + g * 4);
            #pragma unroll
            for (int b2 = 0; b2 < 4; ++b2) {
                int t = b2 * 16 + c;
                u16x4 vq, vk;
                vq[0] = f2bf((acc[0][a2][b2][0] + bq.x) * scale);
                vq[1] = f2bf((acc[0][a2][b2][1] + bq.y) * scale);
                vq[2] = f2bf((acc[0][a2][b2][2] + bq.z) * scale);
                vq[3] = f2bf((acc[0][a2][b2][3] + bq.w) * scale);
                *(u16x4*)(&Q[t * 40 + a2 * 16 + g * 4]) = vq;
                vk[0] = f2bf(acc[1][a2][b2][0] + bk.x);
                vk[1] = f2bf(acc[1][a2][b2][1] + bk.y);
                vk[2] = f2bf(acc[1][a2][b2][2] + bk.z);
                vk[3] = f2bf(acc[1][a2][b2][3] + bk.w);
                *(u16x4*)(&Kl[t * 40 + a2 * 16 + g * 4]) = vk;
                Vt[(a2 * 16 + g * 4 + 0) * 72 + t] = f2bf(acc[2][a2][b2][0] + bv.x);
                Vt[(a2 * 16 + g * 4 + 1) * 72 + t] = f2bf(acc[2][a2][b2][1] + bv.y);
                Vt[(a2 * 16 + g * 4 + 2) * 72 + t] = f2bf(acc[2][a2][b2][2] + bv.z);
                Vt[(a2 * 16 + g * 4 + 3) * 72 + t] = f2bf(acc[2][a2][b2][3] + bv.w);
            }
        }
    }

    // ---- QK^T (K-dim = 32 = one MFMA step) ----
    bf16x8 qf[4], kf[4];
    #pragma unroll
    for (int mt = 0; mt < 4; ++mt) qf[mt] = *(const bf16x8*)(&Q[(mt * 16 + c) * 40 + g * 8]);
    #pragma unroll
    for (int nt = 0; nt < 4; ++nt) kf[nt] = *(const bf16x8*)(&Kl[(nt * 16 + c) * 40 + g * 8]);
    f32x4 S[4][4] = {};
    __builtin_amdgcn_s_setprio(1);
    #pragma unroll
    for (int mt = 0; mt < 4; ++mt)
        #pragma unroll
        for (int nt = 0; nt < 4; ++nt)
            S[mt][nt] = __builtin_amdgcn_mfma_f32_16x16x32_bf16(qf[mt], kf[nt], S[mt][nt], 0, 0, 0);
    __builtin_amdgcn_s_setprio(0);

    // ---- softmax (full row available), P -> LDS (overlays Q/K) ----
    #pragma unroll
    for (int mt = 0; mt < 4; ++mt) {
        #pragma unroll
        for (int r = 0; r < 4; ++r) {
            int i = mt * 16 + g * 4 + r;
            float vals[4];
            #pragma unroll
            for (int nt = 0; nt < 4; ++nt) {
                int j = nt * 16 + c;
                int d = j - i + 63;
                float v = S[mt][nt][r] + bias_w[d > 63 ? 63 : d];
                vals[nt] = (j > i) ? -1e30f : v;
            }
            float mx = fmaxf(fmaxf(vals[0], vals[1]), fmaxf(vals[2], vals[3]));
            #pragma unroll
            for (int off = 1; off < 16; off <<= 1) mx = fmaxf(mx, __shfl_xor(mx, off, 64));
            float sum = 0.f;
            #pragma unroll
            for (int nt = 0; nt < 4; ++nt) { vals[nt] = __expf(vals[nt] - mx); sum += vals[nt]; }
            #pragma unroll
            for (int off = 1; off < 16; off <<= 1) sum += __shfl_xor(sum, off, 64);
            float inv = 1.0f / sum;
            #pragma unroll
            for (int nt = 0; nt < 4; ++nt) P[i * 72 + nt * 16 + c] = f2bf(vals[nt] * inv);
        }
    }

    // ---- PV: O[i][d] ----
    f32x4 O[4][2] = {};
    #pragma unroll
    for (int kk = 0; kk < 2; ++kk) {
        bf16x8 pa[4], vb[2];
        #pragma unroll
        for (int mt = 0; mt < 4; ++mt)
            pa[mt] = *(const bf16x8*)(&P[(mt * 16 + c) * 72 + kk * 32 + g * 8]);
        #pragma unroll
        for (int nt = 0; nt < 2; ++nt)
            vb[nt] = *(const bf16x8*)(&Vt[(nt * 16 + c) * 72 + kk * 32 + g * 8]);
        __builtin_amdgcn_s_setprio(1);
        #pragma unroll
        for (int mt = 0; mt < 4; ++mt)
            #pragma unroll
            for (int nt = 0; nt < 2; ++nt)
                O[mt][nt] = __builtin_amdgcn_mfma_f32_16x16x32_bf16(pa[mt], vb[nt], O[mt][nt], 0, 0, 0);
        __builtin_amdgcn_s_setprio(0);
    }

    __syncthreads();   // all waves done reading xs
    // ---- O -> att (xs region, swizzled units) ----
    #pragma unroll
    for (int mt = 0; mt < 4; ++mt)
        #pragma unroll
        for (int nt = 0; nt < 2; ++nt)
            #pragma unroll
            for (int r = 0; r < 4; ++r) {
                int t  = mt * 16 + g * 4 + r;
                int cg = w * 32 + nt * 16 + c;
                xs[t * 256 + (((cg >> 3) ^ (t & 7)) << 3) + (cg & 7)] = f2bf(O[mt][nt][r]);
            }
    __syncthreads();

    // ---- proj: D[n][t], A = Wp rows (wave's 32 n), B = att rows ----
    f32x4 ap[2][4] = {};
    #pragma unroll
    for (int ks = 0; ks < 8; ++ks) {
        bf16x8 af[2], bx[4];
        #pragma unroll
        for (int a2 = 0; a2 < 2; ++a2)
            af[a2] = *(const bf16x8*)(wproj + (size_t)(w * 32 + a2 * 16 + c) * 256 + ks * 32 + g * 8);
        #pragma unroll
        for (int b2 = 0; b2 < 4; ++b2)
            bx[b2] = *(const bf16x8*)(&xs[(b2 * 16 + c) * 256 + (((ks * 4 + g) ^ c7) << 3)]);
        #pragma unroll
        for (int a2 = 0; a2 < 2; ++a2)
            #pragma unroll
            for (int b2 = 0; b2 < 4; ++b2)
                ap[a2][b2] = __builtin_amdgcn_mfma_f32_16x16x32_bf16(af[a2], bx[b2], ap[a2][b2], 0, 0, 0);
    }
    #pragma unroll
    for (int a2 = 0; a2 < 2; ++a2) {
        int n = w * 32 + a2 * 16 + g * 4;
        float4 pb = *(const float4*)(proj_b + n);
        #pragma unroll
        for (int b2 = 0; b2 < 4; ++b2) {
            int t = b2 * 16 + c;
            float* dst = out + ((size_t)((b * 64 + t) * 512 + 256 + n)) * 576 + hw;
            dst[0]        = ap[a2][b2][0] + pb.x;
            dst[576]      = ap[a2][b2][1] + pb.y;
            dst[2 * 576]  = ap[a2][b2][2] + pb.z;
            dst[3 * 576]  = ap[a2][b2][3] + pb.w;
        }
    }
}

// ---------- launcher ----------
extern "C" void kernel_launch(void* const* d_in, const int* in_sizes, int n_in,
                              void* d_out, int out_size, void* d_ws, size_t ws_size,
                              hipStream_t stream) {
    (void)in_sizes; (void)n_in; (void)out_size;
    const float* x      = (const float*)d_in[0];
    const float* rpb    = (const float*)d_in[1];
    const float* qkv_w  = (const float*)d_in[2];
    const float* qkv_b  = (const float*)d_in[3];
    const float* proj_w = (const float*)d_in[4];
    const float* proj_b = (const float*)d_in[5];
    float* out = (float*)d_out;

    // ws: wq 393216 | wp 131072 | xb 37748736
    char* ws = (char*)d_ws;
    unsigned short* wq = (unsigned short*)ws;
    unsigned short* wp = (unsigned short*)(ws + 393216);
    unsigned short* xb = (unsigned short*)(ws + 524288);
    if (ws_size < (size_t)524288 + 37748736) return;

    cvt_weights<<<1024, 256, 0, stream>>>(qkv_w, proj_w, wq, wp);
    copy_a<<<18432, 256, 0, stream>>>(x, out);
    transpose_b<<<dim3(128, 9), 256, 0, stream>>>(x, xb);
    fused_block<<<1152, 512, 0, stream>>>(xb, wq, wp, qkv_b, proj_b, rpb, out);
}

// Round 5
// 249.960 us; speedup vs baseline: 1.1003x; 1.0814x over previous
//
#include <hip/hip_runtime.h>
#include <hip/hip_bf16.h>

// ---------- types ----------
typedef __attribute__((ext_vector_type(4))) float  f32x4;
typedef __attribute__((ext_vector_type(8))) short  bf16x8;   // 8 bf16 in 4 VGPRs
typedef __attribute__((ext_vector_type(8))) unsigned short u16x8;

union FU { int w[4]; bf16x8 v; };

__device__ __forceinline__ unsigned short f2bf(float f) {
    union { float f; unsigned u; } v; v.f = f;
    unsigned u = v.u;
    unsigned r = u + 0x7fffu + ((u >> 16) & 1u);   // round-to-nearest-even
    return (unsigned short)(r >> 16);
}

__device__ __forceinline__ unsigned cvtpk(float lo, float hi) {
    unsigned r;
    asm("v_cvt_pk_bf16_f32 %0, %1, %2" : "=v"(r) : "v"(lo), "v"(hi));
    return r;
}

__device__ __forceinline__ int selshfl(unsigned lo, unsigned hiw, int srcLane, bool hi) {
    int a = __shfl((int)lo, srcLane, 64);
    int b = __shfl((int)hiw, srcLane, 64);
    return hi ? b : a;
}

__device__ __forceinline__ void gload16(const void* g, void* l) {
    __builtin_amdgcn_global_load_lds((const __attribute__((address_space(1))) unsigned*)g,
                                     (__attribute__((address_space(3))) unsigned*)l, 16, 0, 0);
}

// ---------- problem constants ----------
// B=2, T=64, CH=512, Hs=24, Ws=24, HW=576, P=1152, DIM=256, HEADS=8, HD=32
// xb layout: p-major, xb[(p*64 + t)*256 + c]

// ---------- K0: weights fp32 -> bf16 ----------
__global__ void cvt_weights(const float* __restrict__ qkv_w, const float* __restrict__ proj_w,
                            unsigned short* __restrict__ wq, unsigned short* __restrict__ wp) {
    int i = blockIdx.x * 256 + threadIdx.x;          // 262144 total
    if (i < 196608) wq[i] = f2bf(qkv_w[i]);
    else            wp[i - 196608] = f2bf(proj_w[i - 196608]);
}

// ---------- K2: transpose b-half -> xb[(p*64+t)*256 + c] bf16; also copies a-half ----------
__global__ __launch_bounds__(256) void transpose_b(const float* __restrict__ x,
                                                   unsigned short* __restrict__ xb,
                                                   float* __restrict__ outp) {
    __shared__ unsigned short tile[256][72];
    const int bt  = blockIdx.x;                       // b*64+t
    const int hw0 = blockIdx.y * 64;
    const int tid = threadIdx.x;
    // a-half copy: 256 ch x 64 hw of this slab
    {
        const size_t slab = (size_t)bt * 294912;      // 512*576
        #pragma unroll
        for (int it = 0; it < 16; ++it) {
            int idx = it * 256 + tid;
            int ch  = idx >> 4;
            int off = (idx & 15) * 4;
            size_t o = slab + (size_t)ch * 576 + hw0 + off;
            *(float4*)(outp + o) = *(const float4*)(x + o);
        }
    }
    const float* src = x + ((size_t)bt * 512 + 256) * 576 + hw0;
    const int c_sub = tid >> 4, l16 = tid & 15;
    #pragma unroll
    for (int it = 0; it < 16; ++it) {
        int cc = it * 16 + c_sub;
        const float4 v = *(const float4*)(src + (size_t)cc * 576 + l16 * 4);
        tile[cc][l16 * 4 + 0] = f2bf(v.x);
        tile[cc][l16 * 4 + 1] = f2bf(v.y);
        tile[cc][l16 * 4 + 2] = f2bf(v.z);
        tile[cc][l16 * 4 + 3] = f2bf(v.w);
    }
    __syncthreads();
    const int row = tid >> 2;                 // hw within tile
    const int cs  = (tid & 3) * 64;
    const int b = bt >> 6, t = bt & 63;
    size_t m = ((size_t)(b * 576 + hw0 + row)) * 64 + t;   // p-major
    unsigned short* dst = xb + m * 256 + cs;
    #pragma unroll
    for (int q = 0; q < 8; ++q) {
        u16x8 v;
        #pragma unroll
        for (int u = 0; u < 8; ++u) v[u] = tile[cs + q * 8 + u][row];
        *(u16x8*)(dst + q * 8) = v;
    }
}

// ---------- K3: fused qkv + attention + proj, one block per pixel ----------
// 512 threads = 8 waves; wave w owns head w. LDS 78 KB -> 2 blocks/CU.
// Q, K, P stay in registers; lane-layout fixes via cvt_pk + shfl (g-group permutation).
__global__ __launch_bounds__(512, 4)
void fused_block(
    const unsigned short* __restrict__ xb,
    const unsigned short* __restrict__ wqkv,   // [768][256] bf16
    const unsigned short* __restrict__ wproj,  // [256][256] bf16
    const float* __restrict__ qkv_b,
    const float* __restrict__ proj_b,
    const float* __restrict__ rpb,
    float* __restrict__ out)
{
    __shared__ unsigned short xs[16384];        // 64 t-rows x 256 c (swizzled 16B units); reused as att
    __shared__ unsigned short VtAll[256 * 88];  // V^T[d][t], row stride 88 (16B-aligned, bank-spread)
    __shared__ float bias_s[8][64];             // bias_s[h][d], d = j-i+63 <= 63 for unmasked

    const int tid  = threadIdx.x;
    const int lane = tid & 63, w = tid >> 6;
    const int c = lane & 15, g = lane >> 4;
    const int c7 = c & 7;
    const bool hi = g >= 2;                     // a2/jt-select for the g-group shuffle
    const int lA = c + 16 * ((2 * g) & 3);      // source lane for frag words 0,1
    const int lB = c + 16 * ((2 * g + 1) & 3);  // source lane for frag words 2,3
    const int bid = blockIdx.x;
    const int p  = (bid & 7) * 144 + (bid >> 3);   // XCD-contiguous pixels
    const int b  = p / 576, hw = p % 576;

    // ---- stage xs (32 KB), source pre-swizzled so linear LDS holds swizzled rows
    const unsigned short* src = xb + (size_t)p * 16384;
    #pragma unroll
    for (int it = 0; it < 4; ++it) {
        int U = it * 512 + tid;
        int r = U >> 5, u = U & 31;
        gload16(src + r * 256 + ((u ^ (r & 7)) << 3), &xs[U << 3]);
    }
    bias_s[tid & 7][tid >> 3] = rpb[tid];       // rows 0..63 of rpb -> [h][d]
    __syncthreads();

    const float* bias_w = bias_s[w];

    // ================= pass 1: V  (acc -> VtAll, own rows only) =================
    {
        f32x4 acc[2][4] = {};
        #pragma unroll
        for (int ks = 0; ks < 8; ++ks) {
            bf16x8 bx[4], af[2];
            #pragma unroll
            for (int b2 = 0; b2 < 4; ++b2)
                bx[b2] = *(const bf16x8*)(&xs[(b2 * 16 + c) * 256 + (((ks * 4 + g) ^ c7) << 3)]);
            #pragma unroll
            for (int a2 = 0; a2 < 2; ++a2)
                af[a2] = *(const bf16x8*)(wqkv + (size_t)(512 + w * 32 + a2 * 16 + c) * 256 + ks * 32 + g * 8);
            #pragma unroll
            for (int a2 = 0; a2 < 2; ++a2)
                #pragma unroll
                for (int b2 = 0; b2 < 4; ++b2)
                    acc[a2][b2] = __builtin_amdgcn_mfma_f32_16x16x32_bf16(af[a2], bx[b2], acc[a2][b2], 0, 0, 0);
        }
        #pragma unroll
        for (int a2 = 0; a2 < 2; ++a2) {
            float4 bv = *(const float4*)(qkv_b + 512 + w * 32 + a2 * 16 + g * 4);
            #pragma unroll
            for (int b2 = 0; b2 < 4; ++b2) {
                int t = b2 * 16 + c;
                VtAll[(w * 32 + a2 * 16 + g * 4 + 0) * 88 + t] = f2bf(acc[a2][b2][0] + bv.x);
                VtAll[(w * 32 + a2 * 16 + g * 4 + 1) * 88 + t] = f2bf(acc[a2][b2][1] + bv.y);
                VtAll[(w * 32 + a2 * 16 + g * 4 + 2) * 88 + t] = f2bf(acc[a2][b2][2] + bv.z);
                VtAll[(w * 32 + a2 * 16 + g * 4 + 3) * 88 + t] = f2bf(acc[a2][b2][3] + bv.w);
            }
        }
    }

    // ================= pass 2: K and Q together (stay in registers) =================
    unsigned kpk[2][4][2], qpk[2][4][2];   // [a2][b2][pair]: packed bf16 pairs over r
    {
        f32x4 ak[2][4] = {}, aq[2][4] = {};
        #pragma unroll
        for (int ks = 0; ks < 8; ++ks) {
            bf16x8 bx[4], afk[2], afq[2];
            #pragma unroll
            for (int b2 = 0; b2 < 4; ++b2)
                bx[b2] = *(const bf16x8*)(&xs[(b2 * 16 + c) * 256 + (((ks * 4 + g) ^ c7) << 3)]);
            #pragma unroll
            for (int a2 = 0; a2 < 2; ++a2) {
                afk[a2] = *(const bf16x8*)(wqkv + (size_t)(256 + w * 32 + a2 * 16 + c) * 256 + ks * 32 + g * 8);
                afq[a2] = *(const bf16x8*)(wqkv + (size_t)(      w * 32 + a2 * 16 + c) * 256 + ks * 32 + g * 8);
            }
            #pragma unroll
            for (int a2 = 0; a2 < 2; ++a2)
                #pragma unroll
                for (int b2 = 0; b2 < 4; ++b2) {
                    ak[a2][b2] = __builtin_amdgcn_mfma_f32_16x16x32_bf16(afk[a2], bx[b2], ak[a2][b2], 0, 0, 0);
                    aq[a2][b2] = __builtin_amdgcn_mfma_f32_16x16x32_bf16(afq[a2], bx[b2], aq[a2][b2], 0, 0, 0);
                }
        }
        #pragma unroll
        for (int a2 = 0; a2 < 2; ++a2) {
            float4 bk = *(const float4*)(qkv_b + 256 + w * 32 + a2 * 16 + g * 4);
            float4 bq = *(const float4*)(qkv_b +       w * 32 + a2 * 16 + g * 4);
            #pragma unroll
            for (int b2 = 0; b2 < 4; ++b2) {
                kpk[a2][b2][0] = cvtpk(ak[a2][b2][0] + bk.x, ak[a2][b2][1] + bk.y);
                kpk[a2][b2][1] = cvtpk(ak[a2][b2][2] + bk.z, ak[a2][b2][3] + bk.w);
                qpk[a2][b2][0] = cvtpk(aq[a2][b2][0] + bq.x, aq[a2][b2][1] + bq.y);
                qpk[a2][b2][1] = cvtpk(aq[a2][b2][2] + bq.z, aq[a2][b2][3] + bq.w);
            }
        }
    }

    // ================= QK^T (swapped): S^T[j][i] = mfma(K-frag, Q-frag) =================
    bf16x8 kf[4], qf[4];
    #pragma unroll
    for (int t = 0; t < 4; ++t) {
        FU f;
        f.w[0] = selshfl(kpk[0][t][0], kpk[1][t][0], lA, hi);
        f.w[1] = selshfl(kpk[0][t][1], kpk[1][t][1], lA, hi);
        f.w[2] = selshfl(kpk[0][t][0], kpk[1][t][0], lB, hi);
        f.w[3] = selshfl(kpk[0][t][1], kpk[1][t][1], lB, hi);
        kf[t] = f.v;
        FU f2;
        f2.w[0] = selshfl(qpk[0][t][0], qpk[1][t][0], lA, hi);
        f2.w[1] = selshfl(qpk[0][t][1], qpk[1][t][1], lA, hi);
        f2.w[2] = selshfl(qpk[0][t][0], qpk[1][t][0], lB, hi);
        f2.w[3] = selshfl(qpk[0][t][1], qpk[1][t][1], lB, hi);
        qf[t] = f2.v;
    }
    f32x4 S[4][4];   // S[jt][it]: value (j = 16jt+4g+r, i = 16it+c)
    #pragma unroll
    for (int jt = 0; jt < 4; ++jt)
        #pragma unroll
        for (int it = 0; it < 4; ++it)
            S[jt][it] = f32x4{0.f, 0.f, 0.f, 0.f};
    __builtin_amdgcn_s_setprio(1);
    #pragma unroll
    for (int jt = 0; jt < 4; ++jt)
        #pragma unroll
        for (int it = 0; it < 4; ++it)
            S[jt][it] = __builtin_amdgcn_mfma_f32_16x16x32_bf16(kf[jt], qf[it], S[jt][it], 0, 0, 0);
    __builtin_amdgcn_s_setprio(0);

    // ================= softmax on S^T (row i spread over 4 g-lanes) =================
    const float scale = 0.17677669529663687f;  // 1/sqrt(32)
    unsigned ppk[4][4][2];                      // [jt][it][pair]
    #pragma unroll
    for (int it = 0; it < 4; ++it) {
        float rs = 0.f;
        #pragma unroll
        for (int jt = 0; jt < 4; ++jt)
            #pragma unroll
            for (int r = 0; r < 4; ++r) {
                int j = jt * 16 + 4 * g + r;
                int i = it * 16 + c;
                int d = j - i + 63; d = d > 63 ? 63 : d;
                float v = S[jt][it][r] * scale + bias_w[d];
                float e = (j > i) ? 0.f : __expf(v);
                S[jt][it][r] = e;
                rs += e;
            }
        rs += __shfl_xor(rs, 16, 64);
        rs += __shfl_xor(rs, 32, 64);
        float inv = 1.0f / rs;
        #pragma unroll
        for (int jt = 0; jt < 4; ++jt) {
            ppk[jt][it][0] = cvtpk(S[jt][it][0] * inv, S[jt][it][1] * inv);
            ppk[jt][it][1] = cvtpk(S[jt][it][2] * inv, S[jt][it][3] * inv);
        }
    }

    // ================= PV: O^T[d][i] = mfma(V^T-frag, P-frag) =================
    bf16x8 vf[2][2];
    #pragma unroll
    for (int dt = 0; dt < 2; ++dt)
        #pragma unroll
        for (int kk = 0; kk < 2; ++kk)
            vf[dt][kk] = *(const bf16x8*)(&VtAll[(w * 32 + dt * 16 + c) * 88 + kk * 32 + g * 8]);
    f32x4 O[2][4];   // [dt][it]: value (d = 16dt+4g+r, i = 16it+c)
    #pragma unroll
    for (int dt = 0; dt < 2; ++dt)
        #pragma unroll
        for (int it = 0; it < 4; ++it)
            O[dt][it] = f32x4{0.f, 0.f, 0.f, 0.f};
    #pragma unroll
    for (int it = 0; it < 4; ++it) {
        #pragma unroll
        for (int kk = 0; kk < 2; ++kk) {
            FU pf;
            pf.w[0] = selshfl(ppk[2 * kk][it][0], ppk[2 * kk + 1][it][0], lA, hi);
            pf.w[1] = selshfl(ppk[2 * kk][it][1], ppk[2 * kk + 1][it][1], lA, hi);
            pf.w[2] = selshfl(ppk[2 * kk][it][0], ppk[2 * kk + 1][it][0], lB, hi);
            pf.w[3] = selshfl(ppk[2 * kk][it][1], ppk[2 * kk + 1][it][1], lB, hi);
            __builtin_amdgcn_s_setprio(1);
            #pragma unroll
            for (int dt = 0; dt < 2; ++dt)
                O[dt][it] = __builtin_amdgcn_mfma_f32_16x16x32_bf16(vf[dt][kk], pf.v, O[dt][it], 0, 0, 0);
            __builtin_amdgcn_s_setprio(0);
        }
    }

    __syncthreads();   // all waves done reading xs
    // ---- O -> att (xs region, swizzled units) ----
    #pragma unroll
    for (int dt = 0; dt < 2; ++dt)
        #pragma unroll
        for (int it = 0; it < 4; ++it)
            #pragma unroll
            for (int r = 0; r < 4; ++r) {
                int t  = it * 16 + c;
                int cg = w * 32 + dt * 16 + 4 * g + r;
                xs[t * 256 + ((((cg >> 3) ^ (t & 7)) << 3) | (cg & 7))] = f2bf(O[dt][it][r]);
            }
    __syncthreads();

    // ================= proj: D[n][t], A = Wp rows (wave's 32 n), B = att rows =================
    f32x4 ap[2][4] = {};
    #pragma unroll
    for (int ks = 0; ks < 8; ++ks) {
        bf16x8 af[2], bx[4];
        #pragma unroll
        for (int a2 = 0; a2 < 2; ++a2)
            af[a2] = *(const bf16x8*)(wproj + (size_t)(w * 32 + a2 * 16 + c) * 256 + ks * 32 + g * 8);
        #pragma unroll
        for (int b2 = 0; b2 < 4; ++b2)
            bx[b2] = *(const bf16x8*)(&xs[(b2 * 16 + c) * 256 + (((ks * 4 + g) ^ c7) << 3)]);
        #pragma unroll
        for (int a2 = 0; a2 < 2; ++a2)
            #pragma unroll
            for (int b2 = 0; b2 < 4; ++b2)
                ap[a2][b2] = __builtin_amdgcn_mfma_f32_16x16x32_bf16(af[a2], bx[b2], ap[a2][b2], 0, 0, 0);
    }
    #pragma unroll
    for (int a2 = 0; a2 < 2; ++a2) {
        int n = w * 32 + a2 * 16 + g * 4;
        float4 pb = *(const float4*)(proj_b + n);
        #pragma unroll
        for (int b2 = 0; b2 < 4; ++b2) {
            int t = b2 * 16 + c;
            float* dst = out + ((size_t)((b * 64 + t) * 512 + 256 + n)) * 576 + hw;
            dst[0]        = ap[a2][b2][0] + pb.x;
            dst[576]      = ap[a2][b2][1] + pb.y;
            dst[2 * 576]  = ap[a2][b2][2] + pb.z;
            dst[3 * 576]  = ap[a2][b2][3] + pb.w;
        }
    }
}

// ---------- launcher ----------
extern "C" void kernel_launch(void* const* d_in, const int* in_sizes, int n_in,
                              void* d_out, int out_size, void* d_ws, size_t ws_size,
                              hipStream_t stream) {
    (void)in_sizes; (void)n_in; (void)out_size;
    const float* x      = (const float*)d_in[0];
    const float* rpb    = (const float*)d_in[1];
    const float* qkv_w  = (const float*)d_in[2];
    const float* qkv_b  = (const float*)d_in[3];
    const float* proj_w = (const float*)d_in[4];
    const float* proj_b = (const float*)d_in[5];
    float* out = (float*)d_out;

    // ws: wq 393216 | wp 131072 | xb 37748736
    char* ws = (char*)d_ws;
    unsigned short* wq = (unsigned short*)ws;
    unsigned short* wp = (unsigned short*)(ws + 393216);
    unsigned short* xb = (unsigned short*)(ws + 524288);
    if (ws_size < (size_t)524288 + 37748736) return;

    cvt_weights<<<1024, 256, 0, stream>>>(qkv_w, proj_w, wq, wp);
    transpose_b<<<dim3(128, 9), 256, 0, stream>>>(x, xb, out);
    fused_block<<<1152, 512, 0, stream>>>(xb, wq, wp, qkv_b, proj_b, rpb, out);
}